// Round 1
// baseline (370.699 us; speedup 1.0000x reference)
//
#include <hip/hip_runtime.h>

// BitDelta chained-layer kernel.
// Per layer: W = base[l] + bitdelta[l]*mask[l]; x = x @ W.  x is [16,4096],
// weights [4096,4096] fp32.  Memory-bound on streaming base+mask (537 MB).
//
// Decomposition per layer: grid (KCHUNKS=64, NCHUNKS=4).  Each block owns a
// [KC=64, 1024-col] tile of W, computes partial out[16,1024] and atomicAdds
// into a pre-zeroed accumulator.  Ping-pong activations live in d_ws.

#define DD 4096
#define BB 16
#define KC 64
#define VEC 4
#define TPB 256
#define NCHUNKS (DD / (TPB * VEC))   // 4
#define KCHUNKS (DD / KC)            // 64

__global__ __launch_bounds__(TPB)
void bitdelta_layer(const float* __restrict__ x,
                    const float* __restrict__ base,
                    const float* __restrict__ mask,
                    const float* __restrict__ bitdelta,
                    int layer,
                    float* __restrict__ out) {
    __shared__ float xs[BB][KC];   // x slice [16][64] = 4 KB

    const int k0 = blockIdx.x * KC;
    const int c0 = blockIdx.y * (TPB * VEC) + threadIdx.x * VEC;

    // Stage x[0:16][k0:k0+KC] into LDS (coalesced float4 loads).
    {
        const int idx = threadIdx.x * 4;        // 0..1023
        const int r  = idx >> 6;                // row 0..15
        const int kk = idx & 63;                // col-in-slice, multiple of 4
        *reinterpret_cast<float4*>(&xs[r][kk]) =
            *reinterpret_cast<const float4*>(&x[r * DD + k0 + kk]);
    }
    __syncthreads();

    const float bd = bitdelta[layer];

    float acc[BB][VEC];
#pragma unroll
    for (int r = 0; r < BB; ++r)
#pragma unroll
        for (int j = 0; j < VEC; ++j) acc[r][j] = 0.0f;

    const float* bp = base + (size_t)k0 * DD + c0;
    const float* mp = mask + (size_t)k0 * DD + c0;

    // Depth-1 software pipeline over pairs of W rows.
    float4 b0 = *reinterpret_cast<const float4*>(bp);
    float4 b1 = *reinterpret_cast<const float4*>(bp + DD);
    float4 m0 = *reinterpret_cast<const float4*>(mp);
    float4 m1 = *reinterpret_cast<const float4*>(mp + DD);

#define COMPUTE_PAIR(kk)                                                     \
    do {                                                                     \
        const float w00 = fmaf(bd, m0.x, b0.x);                              \
        const float w01 = fmaf(bd, m0.y, b0.y);                              \
        const float w02 = fmaf(bd, m0.z, b0.z);                              \
        const float w03 = fmaf(bd, m0.w, b0.w);                              \
        const float w10 = fmaf(bd, m1.x, b1.x);                              \
        const float w11 = fmaf(bd, m1.y, b1.y);                              \
        const float w12 = fmaf(bd, m1.z, b1.z);                              \
        const float w13 = fmaf(bd, m1.w, b1.w);                              \
        _Pragma("unroll")                                                    \
        for (int r = 0; r < BB; ++r) {                                       \
            const float2 xv = *reinterpret_cast<const float2*>(&xs[r][kk]);  \
            acc[r][0] = fmaf(xv.x, w00, acc[r][0]);                          \
            acc[r][1] = fmaf(xv.x, w01, acc[r][1]);                          \
            acc[r][2] = fmaf(xv.x, w02, acc[r][2]);                          \
            acc[r][3] = fmaf(xv.x, w03, acc[r][3]);                          \
            acc[r][0] = fmaf(xv.y, w10, acc[r][0]);                          \
            acc[r][1] = fmaf(xv.y, w11, acc[r][1]);                          \
            acc[r][2] = fmaf(xv.y, w12, acc[r][2]);                          \
            acc[r][3] = fmaf(xv.y, w13, acc[r][3]);                          \
        }                                                                    \
    } while (0)

    for (int k = 0; k < KC - 2; k += 2) {
        bp += 2 * DD;
        mp += 2 * DD;
        const float4 nb0 = *reinterpret_cast<const float4*>(bp);
        const float4 nb1 = *reinterpret_cast<const float4*>(bp + DD);
        const float4 nm0 = *reinterpret_cast<const float4*>(mp);
        const float4 nm1 = *reinterpret_cast<const float4*>(mp + DD);

        COMPUTE_PAIR(k);

        b0 = nb0; b1 = nb1; m0 = nm0; m1 = nm1;
    }
    COMPUTE_PAIR(KC - 2);   // tail pair (already loaded)

#undef COMPUTE_PAIR

    // Accumulate partials (one contributor per k-chunk).
#pragma unroll
    for (int r = 0; r < BB; ++r)
#pragma unroll
        for (int j = 0; j < VEC; ++j)
            atomicAdd(&out[r * DD + c0 + j], acc[r][j]);
}

extern "C" void kernel_launch(void* const* d_in, const int* in_sizes, int n_in,
                              void* d_out, int out_size, void* d_ws, size_t ws_size,
                              hipStream_t stream) {
    const float* x    = (const float*)d_in[0];   // [16,4096]
    const float* base = (const float*)d_in[1];   // [4,4096,4096]
    const float* mask = (const float*)d_in[2];   // [4,4096,4096]
    const float* bd   = (const float*)d_in[3];   // [4]
    float* out = (float*)d_out;                  // [16,4096] fp32

    float* y0 = (float*)d_ws;                    // ping
    float* y1 = y0 + BB * DD;                    // pong (256 KB offset)

    const size_t act_bytes    = (size_t)BB * DD * sizeof(float);
    const size_t layer_stride = (size_t)DD * DD;

    const dim3 grid(KCHUNKS, NCHUNKS);

    // layer 0: x -> y0
    hipMemsetAsync(y0, 0, act_bytes, stream);
    bitdelta_layer<<<grid, TPB, 0, stream>>>(x, base, mask, bd, 0, y0);
    // layer 1: y0 -> y1
    hipMemsetAsync(y1, 0, act_bytes, stream);
    bitdelta_layer<<<grid, TPB, 0, stream>>>(y0, base + 1 * layer_stride,
                                             mask + 1 * layer_stride, bd, 1, y1);
    // layer 2: y1 -> y0
    hipMemsetAsync(y0, 0, act_bytes, stream);
    bitdelta_layer<<<grid, TPB, 0, stream>>>(y1, base + 2 * layer_stride,
                                             mask + 2 * layer_stride, bd, 2, y0);
    // layer 3: y0 -> out
    hipMemsetAsync(out, 0, act_bytes, stream);
    bitdelta_layer<<<grid, TPB, 0, stream>>>(y0, base + 3 * layer_stride,
                                             mask + 3 * layer_stride, bd, 3, out);
}